// Round 5
// baseline (4951.778 us; speedup 1.0000x reference)
//
#include <hip/hip_runtime.h>

typedef _Float16 f16;
typedef _Float16 f16x8 __attribute__((ext_vector_type(8)));
typedef float    f32x4 __attribute__((ext_vector_type(4)));

#define S_ 256
#define B_ 64
#define E_ 256
#define H_ 512
#define V_ 10000
#define M_ (S_*B_)       // 16384 = total (t,b) rows
#define VPAD 10112       // 79*128
#define FSTRIDE 32       // u32s between flags: 128B -> one LLC line per flag

// ======================= prep kernels =======================

__global__ void k_trans3(const float* __restrict__ s0, const float* __restrict__ s1,
                         const float* __restrict__ s2, f16* __restrict__ dst,
                         int K, int k0) {
  int idx = blockIdx.x*256 + threadIdx.x;
  if (idx >= 1536*K) return;
  int n = idx / K, k = idx - n*K;
  const float* s = (n < 512) ? s0 : (n < 1024 ? s1 : s2);
  dst[idx] = (f16)s[(size_t)(k0 + k)*H_ + (n & 511)];
}

__global__ void k_transW(const float* __restrict__ src, f16* __restrict__ dst) {
  __shared__ float tile[32][33];
  int tx = threadIdx.x & 31, ty = threadIdx.x >> 5;  // 32x8 threads
  int n0 = blockIdx.x*32, k0 = blockIdx.y*32;
  #pragma unroll
  for (int i = 0; i < 4; ++i) {
    int n = n0 + tx, k = k0 + ty + i*8;
    tile[ty + i*8][tx] = (n < V_) ? src[(size_t)k*V_ + n] : 0.f;
  }
  __syncthreads();
  #pragma unroll
  for (int i = 0; i < 4; ++i) {
    int n = n0 + ty + i*8, k = k0 + tx;
    dst[(size_t)n*H_ + k] = (f16)tile[tx][ty + i*8];
  }
}

__global__ void k_gatherX(const int* __restrict__ tok, const float* __restrict__ emb,
                          f16* __restrict__ X) {
  int idx = blockIdx.x*256 + threadIdx.x;
  int m = idx >> 8, e = idx & 255;
  X[idx] = (f16)emb[(size_t)tok[m]*E_ + e];
}

__global__ void k_bias(const float* r0, const float* z0, const float* h0,
                       const float* r1, const float* z1, const float* h1,
                       float* b0, float* b1) {
  int i = blockIdx.x*256 + threadIdx.x;
  if (i >= 1536) return;
  int g = i >> 9, n = i & 511;
  b0[i] = (g == 0 ? r0 : g == 1 ? z0 : h0)[n];
  b1[i] = (g == 0 ? r1 : g == 1 ? z1 : h1)[n];
}

// ======================= GEMM =======================
template<bool OUT_F32>
__global__ __launch_bounds__(256, 2)
void k_gemm(const f16* __restrict__ A, const f16* __restrict__ Bt,
            const float* __restrict__ bias, void* __restrict__ Cout,
            int Nreal, int K, int ldc) {
  __shared__ f16 As[128*64];
  __shared__ f16 Bs[128*64];
  const int m0 = blockIdx.x*128, n0 = blockIdx.y*128;
  const int tid = threadIdx.x;
  const int l = tid & 63, wid = tid >> 6;
  const int wm = (wid & 1)*64, wn = (wid >> 1)*64;
  const int lm = l & 15, lg = l >> 4;
  f32x4 acc[4][4] = {};

  for (int kt = 0; kt < K; kt += 64) {
    #pragma unroll
    for (int i = 0; i < 4; ++i) {
      int idx = i*256 + tid;
      int row = idx >> 3, ch = idx & 7;
      f16x8 va = *(const f16x8*)(A  + (size_t)(m0+row)*K + kt + ch*8);
      *(f16x8*)(As + row*64 + ((ch ^ (row & 7))*8)) = va;
      f16x8 vb = *(const f16x8*)(Bt + (size_t)(n0+row)*K + kt + ch*8);
      *(f16x8*)(Bs + row*64 + ((ch ^ (row & 7))*8)) = vb;
    }
    __syncthreads();
    #pragma unroll
    for (int ks = 0; ks < 2; ++ks) {
      f16x8 af[4], bf[4];
      #pragma unroll
      for (int mt = 0; mt < 4; ++mt) {
        int row = wm + mt*16 + lm, ch = ks*4 + lg;
        af[mt] = *(const f16x8*)(As + row*64 + ((ch ^ (row & 7))*8));
      }
      #pragma unroll
      for (int nt = 0; nt < 4; ++nt) {
        int col = wn + nt*16 + lm, ch = ks*4 + lg;
        bf[nt] = *(const f16x8*)(Bs + col*64 + ((ch ^ (col & 7))*8));
      }
      #pragma unroll
      for (int mt = 0; mt < 4; ++mt)
        #pragma unroll
        for (int nt = 0; nt < 4; ++nt)
          acc[mt][nt] = __builtin_amdgcn_mfma_f32_16x16x32_f16(af[mt], bf[nt], acc[mt][nt], 0, 0, 0);
    }
    __syncthreads();
  }
  #pragma unroll
  for (int nt = 0; nt < 4; ++nt) {
    int col = n0 + wn + nt*16 + lm;
    if (col >= Nreal) continue;
    float bv = bias[col];
    #pragma unroll
    for (int mt = 0; mt < 4; ++mt) {
      int rbase = m0 + wm + mt*16 + lg*4;
      #pragma unroll
      for (int i = 0; i < 4; ++i) {
        float v = acc[mt][nt][i] + bv;
        if (OUT_F32) ((float*)Cout)[(size_t)(rbase+i)*ldc + col] = v;
        else         ((f16*)Cout)[(size_t)(rbase+i)*ldc + col] = (f16)v;
      }
    }
  }
}

// ======================= fused 2-layer recurrence =======================
// 128 WGs x 192 threads.
//   bids 0..63  : layer-0 WGs (wave 0 only; waves 1,2 exit).
//   bids 64..127: layer-1 WGs: wave 0 consumer, waves 1,2 producers.
// Exchange data packed to 16B/lane via in-wave LDS repack; 2x u64 agent
// stores per destination. Flags: one 128B line each; shadow flag copy for
// producers so they never poll the consumer-critical lines.

struct pk2 { unsigned long long a, b; };

__device__ __forceinline__ f16x8 load8_agent(const f16* p) {
  union { unsigned long long u[2]; f16x8 v; } cv;
  cv.u[0] = __hip_atomic_load((const unsigned long long*)p,     __ATOMIC_RELAXED, __HIP_MEMORY_SCOPE_AGENT);
  cv.u[1] = __hip_atomic_load((const unsigned long long*)p + 1, __ATOMIC_RELAXED, __HIP_MEMORY_SCOPE_AGENT);
  return cv.v;
}

// drain my stores to the coherence point, then publish arrival flag(s)
__device__ __forceinline__ void arrive2(unsigned int* f, unsigned int* fp,
                                        int j, unsigned int nb, int l) {
  asm volatile("s_waitcnt vmcnt(0)" ::: "memory");
  if (l == 0) {
    __hip_atomic_store(f + j*FSTRIDE, nb, __ATOMIC_RELAXED, __HIP_MEMORY_SCOPE_AGENT);
    if (fp)
      __hip_atomic_store(fp + j*FSTRIDE, nb, __ATOMIC_RELAXED, __HIP_MEMORY_SCOPE_AGENT);
  }
}

// wave-local spin until all 16 flags >= nb (flags monotone increasing)
template<bool SLEEP>
__device__ __forceinline__ void waitall16(const unsigned int* flags, unsigned int nb, int l) {
  int idx = (l & 15)*FSTRIDE, guard = 0;
  for (;;) {
    unsigned int v = __hip_atomic_load(flags + idx, __ATOMIC_RELAXED, __HIP_MEMORY_SCOPE_AGENT);
    if (__all((int)(v >= nb))) break;
    if (SLEEP) { __builtin_amdgcn_s_sleep(4); if (++guard > (1 << 21)) break; }
    else       { if (++guard > (1 << 23)) break; }   // tight spin; load latency = backoff
  }
}

__global__ __launch_bounds__(192, 1)
void k_recur_fused(const f16* __restrict__ XG0,   // [M_][1536] layer-0 pre-acts (incl bias)
                   const f16* __restrict__ U0T,   // [1536][512]
                   const f16* __restrict__ U1T,   // [1536][512]
                   const f16* __restrict__ W1xT,  // [1536][512]
                   const float* __restrict__ bias1,
                   f16* __restrict__ H0,          // [M_][512] (agent stores)
                   f16* __restrict__ H1,          // [M_][512] (plain stores)
                   float* __restrict__ hfin0, float* __restrict__ hfin1,
                   f16* __restrict__ h0sh, f16* __restrict__ rh0sh,
                   f16* __restrict__ h1sh, f16* __restrict__ rh1sh,
                   unsigned int* __restrict__ flags0,
                   unsigned int* __restrict__ flags0p,  // shadow for producers
                   unsigned int* __restrict__ flags1) {
  const int bid = blockIdx.x;
  const bool isL1 = bid >= 64;
  const int lbid = isL1 ? bid - 64 : bid;
  const int team = lbid >> 4, j = lbid & 15;
  const int tid = threadIdx.x;
  const int w = tid >> 6;
  const int l = tid & 63, lm = l & 15, lg = l >> 4;

  __shared__ __align__(16) f16 Us[2*32*512];     // Ur|Uz slices, swizzled (64 KB)
  __shared__ __align__(16) f16 xgbuf[2][16][96]; // L1 xg double-buffer (6 KB)
  __shared__ __align__(16) f16 stg[16*40];       // wave-0-private repack tile (1.25 KB)

  if (!isL1 && w != 0) return;        // L0 WGs: single wave, no __syncthreads anywhere

  unsigned int* f0t  = flags0  + team*16*FSTRIDE;
  unsigned int* f0pt = flags0p + team*16*FSTRIDE;
  unsigned int* f1t  = flags1  + team*16*FSTRIDE;

  // ---- packing helpers (wave 0 only touches stg) ----
  // stage own 16x32 tile (values v[nt][i] at row lg*4+i, local col nt*16+lm),
  // repack to 16B/lane: lane l -> row l&15, cols (l>>4)*8..+7
  auto STAGE = [&](const float v[2][4]) -> pk2 {
    #pragma unroll
    for (int nt = 0; nt < 2; ++nt)
      #pragma unroll
      for (int i = 0; i < 4; ++i)
        stg[(lg*4 + i)*40 + nt*16 + lm] = (f16)v[nt][i];
    asm volatile("s_waitcnt lgkmcnt(0)" ::: "memory");
    __builtin_amdgcn_sched_barrier(0);
    pk2 r;
    r.a = *(const unsigned long long*)(stg + lm*40 + lg*8);
    r.b = *(const unsigned long long*)(stg + lm*40 + lg*8 + 4);
    return r;
  };
  auto PUT2 = [&](f16* base, pk2 v) {   // agent 16B to [row=lm][col j*32+lg*8]
    unsigned long long* p = (unsigned long long*)(base + lm*512 + j*32 + lg*8);
    __hip_atomic_store(p,     v.a, __ATOMIC_RELAXED, __HIP_MEMORY_SCOPE_AGENT);
    __hip_atomic_store(p + 1, v.b, __ATOMIC_RELAXED, __HIP_MEMORY_SCOPE_AGENT);
  };
  auto PUT2P = [&](f16* base, pk2 v) {  // plain (cached) 16B
    unsigned long long* p = (unsigned long long*)(base + lm*512 + j*32 + lg*8);
    p[0] = v.a; p[1] = v.b;
  };
  auto OWN8 = [&]() -> f16x8 {          // own A-frag slice from stg
    return *(const f16x8*)(stg + lm*40 + lg*8);
  };

  const int colg[2] = { j*32 + lm, j*32 + 16 + lm };

  // =========================== LAYER 0 ===========================
  if (!isL1) {
    f16* h_sh  = h0sh  + team*(16*512);
    f16* rh_sh = rh0sh + team*(16*512);
    for (int i = l; i < 2*32*64; i += 64) {
      int g = i >> 11, rem = i & 2047;
      int c = rem >> 6, ch = rem & 63;
      f16x8 v = *(const f16x8*)(U0T + (size_t)(g*512 + j*32 + c)*512 + ch*8);
      *(f16x8*)(Us + g*16384 + c*512 + ((ch ^ (c & 7))*8)) = v;
    }
    f16x8 uh[2][16];
    #pragma unroll
    for (int nt = 0; nt < 2; ++nt)
      #pragma unroll
      for (int s = 0; s < 16; ++s)
        uh[nt][s] = *(const f16x8*)(U0T + (size_t)(1024 + j*32 + nt*16 + lm)*512 + s*32 + lg*8);

    float hreg[2][4], zreg[2][4];
    float xr[2][4], xz[2][4], xh[2][4];

    auto PREFX = [&](int tt) {
      const f16* xgp = XG0 + (size_t)(tt*64 + team*16)*1536;
      #pragma unroll
      for (int nt = 0; nt < 2; ++nt)
        #pragma unroll
        for (int i = 0; i < 4; ++i) {
          const f16* p = xgp + (size_t)(lg*4 + i)*1536;
          xr[nt][i] = (float)p[colg[nt]];
          xz[nt][i] = (float)p[512  + colg[nt]];
          xh[nt][i] = (float)p[1024 + colg[nt]];
        }
    };

    // ---- t = 0
    PREFX(0);
    {
      float hv[2][4];
      #pragma unroll
      for (int nt = 0; nt < 2; ++nt)
        #pragma unroll
        for (int i = 0; i < 4; ++i) {
          float z = 1.f/(1.f + __expf(-xz[nt][i]));
          float c = 1.f - 2.f/(__expf(2.f*xh[nt][i]) + 1.f);
          hv[nt][i] = z*c;
          hreg[nt][i] = hv[nt][i];
        }
      pk2 pk = STAGE(hv);
      PUT2(h_sh, pk);
      PUT2(H0 + (size_t)(team*16)*512, pk);
    }
    arrive2(f0t, f0pt, j, 1, l);
    PREFX(1);                 // prefetch hides under the spin
    waitall16<false>(f0t, 1, l);

    for (int t = 1; t < S_; ++t) {
      // ---- phase A: r,z
      f16x8 af[16];
      #pragma unroll
      for (int s = 0; s < 16; ++s)
        if (s != j) af[s] = load8_agent(h_sh + lm*512 + lg*8 + s*32);
      af[j] = OWN8();           // own h(t-1) still staged in stg
      f32x4 accr[2] = {}, accz[2] = {};
      #pragma unroll
      for (int s = 0; s < 16; ++s) {
        #pragma unroll
        for (int nt = 0; nt < 2; ++nt) {
          int colL = nt*16 + lm, ch = s*4 + lg;
          f16x8 br = *(const f16x8*)(Us +         colL*512 + ((ch ^ (colL & 7))*8));
          f16x8 bz = *(const f16x8*)(Us + 16384 + colL*512 + ((ch ^ (colL & 7))*8));
          accr[nt] = __builtin_amdgcn_mfma_f32_16x16x32_f16(af[s], br, accr[nt], 0, 0, 0);
          accz[nt] = __builtin_amdgcn_mfma_f32_16x16x32_f16(af[s], bz, accz[nt], 0, 0, 0);
        }
      }
      {
        float rv[2][4];
        #pragma unroll
        for (int nt = 0; nt < 2; ++nt)
          #pragma unroll
          for (int i = 0; i < 4; ++i) {
            float r = 1.f/(1.f + __expf(-(accr[nt][i] + xr[nt][i])));
            float z = 1.f/(1.f + __expf(-(accz[nt][i] + xz[nt][i])));
            zreg[nt][i] = z;
            rv[nt][i] = r*hreg[nt][i];
          }
        pk2 pk = STAGE(rv);     // overwrites stg (h already consumed)
        PUT2(rh_sh, pk);
      }
      arrive2(f0t, nullptr, j, 2*t, l);
      waitall16<false>(f0t, 2*t, l);

      // ---- phase B: cand + h update
      #pragma unroll
      for (int s = 0; s < 16; ++s)
        if (s != j) af[s] = load8_agent(rh_sh + lm*512 + lg*8 + s*32);
      af[j] = OWN8();           // own rh from stg
      f32x4 accc[2] = {};
      #pragma unroll
      for (int s = 0; s < 16; ++s)
        #pragma unroll
        for (int nt = 0; nt < 2; ++nt)
          accc[nt] = __builtin_amdgcn_mfma_f32_16x16x32_f16(af[s], uh[nt][s], accc[nt], 0, 0, 0);
      {
        float hv[2][4];
        #pragma unroll
        for (int nt = 0; nt < 2; ++nt)
          #pragma unroll
          for (int i = 0; i < 4; ++i) {
            float c  = 1.f - 2.f/(__expf(2.f*(accc[nt][i] + xh[nt][i])) + 1.f);
            float z  = zreg[nt][i];
            float hn = (1.f - z)*hreg[nt][i] + z*c;
            hreg[nt][i] = hn;
            hv[nt][i] = hn;
          }
        pk2 pk = STAGE(hv);
        if (t < S_ - 1) PUT2(h_sh, pk);
        PUT2(H0 + (size_t)(t*64 + team*16)*512, pk);
      }
      if (t < S_ - 1) {
        arrive2(f0t, f0pt, j, 2*t + 1, l);
        PREFX(t + 1);
        waitall16<false>(f0t, 2*t + 1, l);
      } else {
        #pragma unroll
        for (int nt = 0; nt < 2; ++nt)
          #pragma unroll
          for (int i = 0; i < 4; ++i)
            hfin0[(team*16 + lg*4 + i)*512 + colg[nt]] = hreg[nt][i];
        arrive2(f0t, f0pt, j, 2*t + 1, l);   // publish final h0; no wait
      }
    }
    return;
  }

  // =========================== LAYER 1 ===========================
  f16* h_sh  = h1sh  + team*(16*512);
  f16* rh_sh = rh1sh + team*(16*512);

  f16x8 uh[2][16];        // consumer only
  f16x8 wx[3][16];        // producers only
  float bv[3];
  if (w == 0) {
    for (int i = l; i < 2*32*64; i += 64) {
      int g = i >> 11, rem = i & 2047;
      int c = rem >> 6, ch = rem & 63;
      f16x8 v = *(const f16x8*)(U1T + (size_t)(g*512 + j*32 + c)*512 + ch*8);
      *(f16x8*)(Us + g*16384 + c*512 + ((ch ^ (c & 7))*8)) = v;
    }
    #pragma unroll
    for (int nt = 0; nt < 2; ++nt)
      #pragma unroll
      for (int s = 0; s < 16; ++s)
        uh[nt][s] = *(const f16x8*)(U1T + (size_t)(1024 + j*32 + nt*16 + lm)*512 + s*32 + lg*8);
  } else {
    const int cb = (w - 1)*3;
    #pragma unroll
    for (int c = 0; c < 3; ++c) {
      int chunk = cb + c, g = chunk >> 1, ntl = chunk & 1;
      int row = g*512 + j*32 + ntl*16 + lm;
      bv[c] = bias1[row];
      #pragma unroll
      for (int s = 0; s < 16; ++s)
        wx[c][s] = *(const f16x8*)(W1xT + (size_t)row*512 + s*32 + lg*8);
    }
  }

  const int cb = (w - 1)*3;
  auto PROD = [&](int tt) {   // producers: xg1(tt) -> xgbuf[tt&1]
    waitall16<true>(f0pt, 2*(unsigned)tt + 1, l);     // shadow flags only
    f16x8 af[16];
    #pragma unroll
    for (int s = 0; s < 16; ++s)
      af[s] = load8_agent(H0 + (size_t)(tt*64 + team*16 + lm)*512 + s*32 + lg*8);
    f32x4 acc[3] = {};
    #pragma unroll
    for (int s = 0; s < 16; ++s)
      #pragma unroll
      for (int c = 0; c < 3; ++c)
        acc[c] = __builtin_amdgcn_mfma_f32_16x16x32_f16(af[s], wx[c][s], acc[c], 0, 0, 0);
    #pragma unroll
    for (int c = 0; c < 3; ++c) {
      int chunk = cb + c, g = chunk >> 1, ntl = chunk & 1;
      #pragma unroll
      for (int i = 0; i < 4; ++i)
        xgbuf[tt & 1][lg*4 + i][g*32 + ntl*16 + lm] = (f16)(acc[c][i] + bv[c]);
    }
  };

  float hreg[2][4], zreg[2][4];

  __syncthreads();                    // init done
  if (w != 0) PROD(0);
  __syncthreads();                    // xg(0) ready

  // ---- t = 0
  if (w == 0) {
    float hv[2][4];
    #pragma unroll
    for (int nt = 0; nt < 2; ++nt)
      #pragma unroll
      for (int i = 0; i < 4; ++i) {
        int row = lg*4 + i;
        float xzv = (float)xgbuf[0][row][32 + nt*16 + lm];
        float xhv = (float)xgbuf[0][row][64 + nt*16 + lm];
        float z = 1.f/(1.f + __expf(-xzv));
        float c = 1.f - 2.f/(__expf(2.f*xhv) + 1.f);
        hv[nt][i] = z*c;
        hreg[nt][i] = hv[nt][i];
      }
    pk2 pk = STAGE(hv);
    PUT2(h_sh, pk);
    PUT2P(H1 + (size_t)(team*16)*512, pk);
    arrive2(f1t, nullptr, j, 1, l);
    waitall16<false>(f1t, 1, l);
  } else {
    PROD(1);
  }
  __syncthreads();                    // xg(1) ready, t=0 exchanged

  for (int t = 1; t < S_; ++t) {
    if (w == 0) {
      const int b = t & 1;
      // ---- phase A
      f16x8 af[16];
      #pragma unroll
      for (int s = 0; s < 16; ++s)
        if (s != j) af[s] = load8_agent(h_sh + lm*512 + lg*8 + s*32);
      af[j] = OWN8();
      f32x4 accr[2] = {}, accz[2] = {};
      #pragma unroll
      for (int s = 0; s < 16; ++s) {
        #pragma unroll
        for (int nt = 0; nt < 2; ++nt) {
          int colL = nt*16 + lm, ch = s*4 + lg;
          f16x8 br = *(const f16x8*)(Us +         colL*512 + ((ch ^ (colL & 7))*8));
          f16x8 bz = *(const f16x8*)(Us + 16384 + colL*512 + ((ch ^ (colL & 7))*8));
          accr[nt] = __builtin_amdgcn_mfma_f32_16x16x32_f16(af[s], br, accr[nt], 0, 0, 0);
          accz[nt] = __builtin_amdgcn_mfma_f32_16x16x32_f16(af[s], bz, accz[nt], 0, 0, 0);
        }
      }
      {
        float rv[2][4];
        #pragma unroll
        for (int nt = 0; nt < 2; ++nt)
          #pragma unroll
          for (int i = 0; i < 4; ++i) {
            int row = lg*4 + i;
            float xrv = (float)xgbuf[b][row][     nt*16 + lm];
            float xzv = (float)xgbuf[b][row][32 + nt*16 + lm];
            float r = 1.f/(1.f + __expf(-(accr[nt][i] + xrv)));
            float z = 1.f/(1.f + __expf(-(accz[nt][i] + xzv)));
            zreg[nt][i] = z;
            rv[nt][i] = r*hreg[nt][i];
          }
        pk2 pk = STAGE(rv);
        PUT2(rh_sh, pk);
      }
      arrive2(f1t, nullptr, j, 2*t, l);
      waitall16<false>(f1t, 2*t, l);

      // ---- phase B
      #pragma unroll
      for (int s = 0; s < 16; ++s)
        if (s != j) af[s] = load8_agent(rh_sh + lm*512 + lg*8 + s*32);
      af[j] = OWN8();
      f32x4 accc[2] = {};
      #pragma unroll
      for (int s = 0; s < 16; ++s)
        #pragma unroll
        for (int nt = 0; nt < 2; ++nt)
          accc[nt] = __builtin_amdgcn_mfma_f32_16x16x32_f16(af[s], uh[nt][s], accc[nt], 0, 0, 0);
      {
        float hv[2][4];
        #pragma unroll
        for (int nt = 0; nt < 2; ++nt)
          #pragma unroll
          for (int i = 0; i < 4; ++i) {
            int row = lg*4 + i;
            float xhv = (float)xgbuf[b][row][64 + nt*16 + lm];
            float c  = 1.f - 2.f/(__expf(2.f*(accc[nt][i] + xhv)) + 1.f);
            float z  = zreg[nt][i];
            float hn = (1.f - z)*hreg[nt][i] + z*c;
            hreg[nt][i] = hn;
            hv[nt][i] = hn;
          }
        pk2 pk = STAGE(hv);
        if (t < S_ - 1) PUT2(h_sh, pk);
        PUT2P(H1 + (size_t)(t*64 + team*16)*512, pk);
      }
      if (t < S_ - 1) {
        arrive2(f1t, nullptr, j, 2*t + 1, l);
        waitall16<false>(f1t, 2*t + 1, l);
      } else {
        #pragma unroll
        for (int nt = 0; nt < 2; ++nt)
          #pragma unroll
          for (int i = 0; i < 4; ++i)
            hfin1[(team*16 + lg*4 + i)*512 + colg[nt]] = hreg[nt][i];
      }
    } else if (t + 1 < S_) {
      PROD(t + 1);
    }
    __syncthreads();
  }
}

// ======================= launch =======================
extern "C" void kernel_launch(void* const* d_in, const int* in_sizes, int n_in,
                              void* d_out, int out_size, void* d_ws, size_t ws_size,
                              hipStream_t stream) {
  const int*   tok  = (const int*)d_in[0];
  const float* emb  = (const float*)d_in[2];
  const float* Wr0  = (const float*)d_in[3];
  const float* br0  = (const float*)d_in[4];
  const float* Wz0  = (const float*)d_in[5];
  const float* bz0  = (const float*)d_in[6];
  const float* Wh0  = (const float*)d_in[7];
  const float* bh0  = (const float*)d_in[8];
  const float* Wr1  = (const float*)d_in[9];
  const float* br1  = (const float*)d_in[10];
  const float* Wz1  = (const float*)d_in[11];
  const float* bz1  = (const float*)d_in[12];
  const float* Wh1  = (const float*)d_in[13];
  const float* bh1  = (const float*)d_in[14];
  const float* Wout = (const float*)d_in[15];
  const float* bout = (const float*)d_in[16];

  char* ws = (char*)d_ws;
  size_t off = 0;
  auto alloc = [&](size_t bytes) { void* p = ws + off; off = (off + bytes + 255) & ~(size_t)255; return p; };
  f16* X     = (f16*)alloc((size_t)M_*E_*2);
  f16* W0xT  = (f16*)alloc((size_t)1536*256*2);
  f16* U0T   = (f16*)alloc((size_t)1536*512*2);
  f16* W1xT  = (f16*)alloc((size_t)1536*512*2);
  f16* U1T   = (f16*)alloc((size_t)1536*512*2);
  f16* WoutT = (f16*)alloc((size_t)VPAD*512*2);
  f16* XG    = (f16*)alloc((size_t)M_*1536*2);
  f16* H0    = (f16*)alloc((size_t)M_*512*2);
  f16* H1    = (f16*)alloc((size_t)M_*512*2);
  f16* h0sh  = (f16*)alloc(4*16*512*2);
  f16* rh0sh = (f16*)alloc(4*16*512*2);
  f16* h1sh  = (f16*)alloc(4*16*512*2);
  f16* rh1sh = (f16*)alloc(4*16*512*2);
  float* bias0 = (float*)alloc(1536*4);
  float* bias1 = (float*)alloc(1536*4);
  unsigned int* flags0  = (unsigned int*)alloc(4*16*FSTRIDE*4);
  unsigned int* flags0p = (unsigned int*)alloc(4*16*FSTRIDE*4);
  unsigned int* flags1  = (unsigned int*)alloc(4*16*FSTRIDE*4);

  float* logits = (float*)d_out;
  float* hfin0  = logits + (size_t)M_*V_;     // [2][64][512] tail
  float* hfin1  = hfin0 + 64*512;

  hipMemsetAsync(flags0,  0, 4*16*FSTRIDE*4, stream);
  hipMemsetAsync(flags0p, 0, 4*16*FSTRIDE*4, stream);
  hipMemsetAsync(flags1,  0, 4*16*FSTRIDE*4, stream);

  k_trans3<<<(1536*256 + 255)/256, 256, 0, stream>>>(Wr0, Wz0, Wh0, W0xT, 256, 0);
  k_trans3<<<(1536*512 + 255)/256, 256, 0, stream>>>(Wr0, Wz0, Wh0, U0T, 512, 256);
  k_trans3<<<(1536*512 + 255)/256, 256, 0, stream>>>(Wr1, Wz1, Wh1, W1xT, 512, 0);
  k_trans3<<<(1536*512 + 255)/256, 256, 0, stream>>>(Wr1, Wz1, Wh1, U1T, 512, 512);
  { dim3 g(VPAD/32, 512/32); k_transW<<<g, 256, 0, stream>>>(Wout, WoutT); }
  k_gatherX<<<(M_*E_)/256, 256, 0, stream>>>(tok, emb, X);
  k_bias<<<6, 256, 0, stream>>>(br0, bz0, bh0, br1, bz1, bh1, bias0, bias1);

  dim3 gx(M_/128, 1536/128);
  k_gemm<false><<<gx, 256, 0, stream>>>(X, W0xT, bias0, XG, 1536, 256, 1536);

  k_recur_fused<<<128, 192, 0, stream>>>(XG, U0T, U1T, W1xT, bias1,
                                         H0, H1, hfin0, hfin1,
                                         h0sh, rh0sh, h1sh, rh1sh,
                                         flags0, flags0p, flags1);

  dim3 gl(M_/128, VPAD/128);
  k_gemm<true><<<gl, 256, 0, stream>>>(H1, WoutT, bout, logits, V_, 512, V_);
}

// Round 8
// 3174.259 us; speedup vs baseline: 1.5600x; 1.5600x over previous
//
#include <hip/hip_runtime.h>

typedef _Float16 f16;
typedef _Float16 f16x8 __attribute__((ext_vector_type(8)));
typedef float    f32x4 __attribute__((ext_vector_type(4)));

#define S_ 256
#define B_ 64
#define E_ 256
#define H_ 512
#define V_ 10000
#define M_ (S_*B_)       // 16384 = total (t,b) rows
#define VPAD 10112       // 79*128
#define FSTRIDE 32       // u32s between flags: 128B -> one line per flag

// ======================= prep kernels =======================

__global__ void k_trans3(const float* __restrict__ s0, const float* __restrict__ s1,
                         const float* __restrict__ s2, f16* __restrict__ dst,
                         int K, int k0) {
  int idx = blockIdx.x*256 + threadIdx.x;
  if (idx >= 1536*K) return;
  int n = idx / K, k = idx - n*K;
  const float* s = (n < 512) ? s0 : (n < 1024 ? s1 : s2);
  dst[idx] = (f16)s[(size_t)(k0 + k)*H_ + (n & 511)];
}

__global__ void k_transW(const float* __restrict__ src, f16* __restrict__ dst) {
  __shared__ float tile[32][33];
  int tx = threadIdx.x & 31, ty = threadIdx.x >> 5;  // 32x8 threads
  int n0 = blockIdx.x*32, k0 = blockIdx.y*32;
  #pragma unroll
  for (int i = 0; i < 4; ++i) {
    int n = n0 + tx, k = k0 + ty + i*8;
    tile[ty + i*8][tx] = (n < V_) ? src[(size_t)k*V_ + n] : 0.f;
  }
  __syncthreads();
  #pragma unroll
  for (int i = 0; i < 4; ++i) {
    int n = n0 + ty + i*8, k = k0 + tx;
    dst[(size_t)n*H_ + k] = (f16)tile[tx][ty + i*8];
  }
}

__global__ void k_gatherX(const int* __restrict__ tok, const float* __restrict__ emb,
                          f16* __restrict__ X) {
  int idx = blockIdx.x*256 + threadIdx.x;
  int m = idx >> 8, e = idx & 255;
  X[idx] = (f16)emb[(size_t)tok[m]*E_ + e];
}

__global__ void k_bias(const float* r0, const float* z0, const float* h0,
                       const float* r1, const float* z1, const float* h1,
                       float* b0, float* b1) {
  int i = blockIdx.x*256 + threadIdx.x;
  if (i >= 1536) return;
  int g = i >> 9, n = i & 511;
  b0[i] = (g == 0 ? r0 : g == 1 ? z0 : h0)[n];
  b1[i] = (g == 0 ? r1 : g == 1 ? z1 : h1)[n];
}

// ======================= GEMM =======================
template<bool OUT_F32>
__global__ __launch_bounds__(256, 2)
void k_gemm(const f16* __restrict__ A, const f16* __restrict__ Bt,
            const float* __restrict__ bias, void* __restrict__ Cout,
            int Nreal, int K, int ldc) {
  __shared__ f16 As[128*64];
  __shared__ f16 Bs[128*64];
  const int m0 = blockIdx.x*128, n0 = blockIdx.y*128;
  const int tid = threadIdx.x;
  const int l = tid & 63, wid = tid >> 6;
  const int wm = (wid & 1)*64, wn = (wid >> 1)*64;
  const int lm = l & 15, lg = l >> 4;
  f32x4 acc[4][4] = {};

  for (int kt = 0; kt < K; kt += 64) {
    #pragma unroll
    for (int i = 0; i < 4; ++i) {
      int idx = i*256 + tid;
      int row = idx >> 3, ch = idx & 7;
      f16x8 va = *(const f16x8*)(A  + (size_t)(m0+row)*K + kt + ch*8);
      *(f16x8*)(As + row*64 + ((ch ^ (row & 7))*8)) = va;
      f16x8 vb = *(const f16x8*)(Bt + (size_t)(n0+row)*K + kt + ch*8);
      *(f16x8*)(Bs + row*64 + ((ch ^ (row & 7))*8)) = vb;
    }
    __syncthreads();
    #pragma unroll
    for (int ks = 0; ks < 2; ++ks) {
      f16x8 af[4], bf[4];
      #pragma unroll
      for (int mt = 0; mt < 4; ++mt) {
        int row = wm + mt*16 + lm, ch = ks*4 + lg;
        af[mt] = *(const f16x8*)(As + row*64 + ((ch ^ (row & 7))*8));
      }
      #pragma unroll
      for (int nt = 0; nt < 4; ++nt) {
        int col = wn + nt*16 + lm, ch = ks*4 + lg;
        bf[nt] = *(const f16x8*)(Bs + col*64 + ((ch ^ (col & 7))*8));
      }
      #pragma unroll
      for (int mt = 0; mt < 4; ++mt)
        #pragma unroll
        for (int nt = 0; nt < 4; ++nt)
          acc[mt][nt] = __builtin_amdgcn_mfma_f32_16x16x32_f16(af[mt], bf[nt], acc[mt][nt], 0, 0, 0);
    }
    __syncthreads();
  }
  #pragma unroll
  for (int nt = 0; nt < 4; ++nt) {
    int col = n0 + wn + nt*16 + lm;
    if (col >= Nreal) continue;
    float bv = bias[col];
    #pragma unroll
    for (int mt = 0; mt < 4; ++mt) {
      int rbase = m0 + wm + mt*16 + lg*4;
      #pragma unroll
      for (int i = 0; i < 4; ++i) {
        float v = acc[mt][nt][i] + bv;
        if (OUT_F32) ((float*)Cout)[(size_t)(rbase+i)*ldc + col] = v;
        else         ((f16*)Cout)[(size_t)(rbase+i)*ldc + col] = (f16)v;
      }
    }
  }
}

// ======================= fused 2-layer recurrence =======================
// 128 WGs x 192 threads (round-4 proven protocol).
//   bids 0..63  : layer-0 WGs (wave 0 only; waves 1,2 exit).
//   bids 64..127: layer-1 WGs: wave 0 consumer, waves 1,2 producers.
// Deltas vs round 4: (1) H0 stores issued AFTER the critical-path ARRIVE
// (during the wait window); producer shadow flag f0pt published one phase
// late, at the next ARRIVE whose vmcnt(0) has drained them. (2) producers
// back off with s_sleep(8) to halve IC poll traffic.

__device__ __forceinline__ f16x8 load8_agent(const f16* p) {
  union { unsigned long long u[2]; f16x8 v; } cv;
  cv.u[0] = __hip_atomic_load((const unsigned long long*)p,     __ATOMIC_RELAXED, __HIP_MEMORY_SCOPE_AGENT);
  cv.u[1] = __hip_atomic_load((const unsigned long long*)p + 1, __ATOMIC_RELAXED, __HIP_MEMORY_SCOPE_AGENT);
  return cv.v;
}

__device__ __forceinline__ void store2_agent(f16* p, f16 v) {
  union { f16 h; unsigned short u; } cv; cv.h = v;
  __hip_atomic_store((unsigned short*)p, cv.u, __ATOMIC_RELAXED, __HIP_MEMORY_SCOPE_AGENT);
}

// drain prior stores to the coherence point, then publish arrival flag(s);
// f gets nbf, fp (if non-null) gets nbp (may differ -> lagged shadow flag).
__device__ __forceinline__ void arrive3(unsigned int* f, unsigned nbf,
                                        unsigned int* fp, unsigned nbp,
                                        int j, int l) {
  asm volatile("s_waitcnt vmcnt(0)" ::: "memory");
  if (l == 0) {
    __hip_atomic_store(f + j*FSTRIDE, nbf, __ATOMIC_RELAXED, __HIP_MEMORY_SCOPE_AGENT);
    if (fp)
      __hip_atomic_store(fp + j*FSTRIDE, nbp, __ATOMIC_RELAXED, __HIP_MEMORY_SCOPE_AGENT);
  }
}

// wave-local spin until all 16 flags >= nb (flags monotone increasing)
template<bool SLEEP>
__device__ __forceinline__ void waitall16(const unsigned int* flags, unsigned int nb, int l) {
  int idx = (l & 15)*FSTRIDE, guard = 0;
  for (;;) {
    unsigned int v = __hip_atomic_load(flags + idx, __ATOMIC_RELAXED, __HIP_MEMORY_SCOPE_AGENT);
    if (__all((int)(v >= nb))) break;
    if (SLEEP) { __builtin_amdgcn_s_sleep(8); if (++guard > (1 << 21)) break; }
    else       { if (++guard > (1 << 23)) break; }   // tight spin; load latency = backoff
  }
}

__global__ __launch_bounds__(192, 1)
void k_recur_fused(const f16* __restrict__ XG0,   // [M_][1536] layer-0 pre-acts (incl bias)
                   const f16* __restrict__ U0T,   // [1536][512]
                   const f16* __restrict__ U1T,   // [1536][512]
                   const f16* __restrict__ W1xT,  // [1536][512]
                   const float* __restrict__ bias1,
                   f16* __restrict__ H0,          // [M_][512] (agent stores, deferred)
                   f16* __restrict__ H1,          // [M_][512] (plain stores)
                   float* __restrict__ hfin0, float* __restrict__ hfin1,
                   f16* __restrict__ h0sh, f16* __restrict__ rh0sh,
                   f16* __restrict__ h1sh, f16* __restrict__ rh1sh,
                   unsigned int* __restrict__ flags0,
                   unsigned int* __restrict__ flags0p,  // shadow for producers (lagged)
                   unsigned int* __restrict__ flags1) {
  const int bid = blockIdx.x;
  const bool isL1 = bid >= 64;
  const int lbid = isL1 ? bid - 64 : bid;
  const int team = lbid >> 4, j = lbid & 15;
  const int tid = threadIdx.x;
  const int w = tid >> 6;
  const int l = tid & 63, lm = l & 15, lg = l >> 4;

  __shared__ __align__(16) f16 Us[2*32*512];     // Ur|Uz slices, swizzled (64 KB)
  __shared__ __align__(16) f16 xgbuf[2][16][96]; // L1 xg double-buffer (6 KB)

  if (!isL1 && w != 0) return;        // L0 WGs: single wave, no __syncthreads anywhere

  unsigned int* f0t  = flags0  + team*16*FSTRIDE;
  unsigned int* f0pt = flags0p + team*16*FSTRIDE;
  unsigned int* f1t  = flags1  + team*16*FSTRIDE;

  const int colg[2] = { j*32 + lm, j*32 + 16 + lm };

  // =========================== LAYER 0 ===========================
  if (!isL1) {
    f16* h_sh  = h0sh  + team*(16*512);
    f16* rh_sh = rh0sh + team*(16*512);
    for (int i = l; i < 2*32*64; i += 64) {
      int g = i >> 11, rem = i & 2047;
      int c = rem >> 6, ch = rem & 63;
      f16x8 v = *(const f16x8*)(U0T + (size_t)(g*512 + j*32 + c)*512 + ch*8);
      *(f16x8*)(Us + g*16384 + c*512 + ((ch ^ (c & 7))*8)) = v;
    }
    f16x8 uh[2][16];
    #pragma unroll
    for (int nt = 0; nt < 2; ++nt)
      #pragma unroll
      for (int s = 0; s < 16; ++s)
        uh[nt][s] = *(const f16x8*)(U0T + (size_t)(1024 + j*32 + nt*16 + lm)*512 + s*32 + lg*8);

    float hreg[2][4], zreg[2][4];
    float xr[2][4], xz[2][4], xh[2][4];

    auto PREFX = [&](int tt) {
      const f16* xgp = XG0 + (size_t)(tt*64 + team*16)*1536;
      #pragma unroll
      for (int nt = 0; nt < 2; ++nt)
        #pragma unroll
        for (int i = 0; i < 4; ++i) {
          const f16* p = xgp + (size_t)(lg*4 + i)*1536;
          xr[nt][i] = (float)p[colg[nt]];
          xz[nt][i] = (float)p[512  + colg[nt]];
          xh[nt][i] = (float)p[1024 + colg[nt]];
        }
    };
    auto STOREH0 = [&](int tt) {   // deferred producer feed (off critical path)
      #pragma unroll
      for (int nt = 0; nt < 2; ++nt)
        #pragma unroll
        for (int i = 0; i < 4; ++i)
          store2_agent(H0 + (size_t)(tt*64 + team*16 + lg*4 + i)*512 + colg[nt],
                       (f16)hreg[nt][i]);
    };

    // ---- t = 0
    PREFX(0);
    #pragma unroll
    for (int nt = 0; nt < 2; ++nt)
      #pragma unroll
      for (int i = 0; i < 4; ++i) {
        int row = lg*4 + i;
        float z = 1.f/(1.f + __expf(-xz[nt][i]));
        float c = 1.f - 2.f/(__expf(2.f*xh[nt][i]) + 1.f);
        float hn = z*c;
        hreg[nt][i] = hn;
        store2_agent(h_sh + row*512 + colg[nt], (f16)hn);
      }
    arrive3(f0t, 1, nullptr, 0, j, l);
    STOREH0(0);               // drained by phase A(1)'s arrive -> f0pt=1 there
    PREFX(1);
    waitall16<false>(f0t, 1, l);

    for (int t = 1; t < S_; ++t) {
      // ---- phase A: r,z
      f16x8 af[16];
      #pragma unroll
      for (int s = 0; s < 16; ++s)
        af[s] = load8_agent(h_sh + lm*512 + lg*8 + s*32);
      f32x4 accr[2] = {}, accz[2] = {};
      #pragma unroll
      for (int s = 0; s < 16; ++s) {
        #pragma unroll
        for (int nt = 0; nt < 2; ++nt) {
          int colL = nt*16 + lm, ch = s*4 + lg;
          f16x8 br = *(const f16x8*)(Us +         colL*512 + ((ch ^ (colL & 7))*8));
          f16x8 bz = *(const f16x8*)(Us + 16384 + colL*512 + ((ch ^ (colL & 7))*8));
          accr[nt] = __builtin_amdgcn_mfma_f32_16x16x32_f16(af[s], br, accr[nt], 0, 0, 0);
          accz[nt] = __builtin_amdgcn_mfma_f32_16x16x32_f16(af[s], bz, accz[nt], 0, 0, 0);
        }
      }
      #pragma unroll
      for (int nt = 0; nt < 2; ++nt)
        #pragma unroll
        for (int i = 0; i < 4; ++i) {
          int row = lg*4 + i;
          float r = 1.f/(1.f + __expf(-(accr[nt][i] + xr[nt][i])));
          float z = 1.f/(1.f + __expf(-(accz[nt][i] + xz[nt][i])));
          zreg[nt][i] = z;
          store2_agent(rh_sh + row*512 + colg[nt], (f16)(r*hreg[nt][i]));
        }
      // vmcnt(0) here also drains the H0(t-1) stores -> publish f0pt=2t-1
      arrive3(f0t, 2*t, f0pt, 2*t - 1, j, l);
      waitall16<false>(f0t, 2*t, l);

      // ---- phase B: cand + h update
      #pragma unroll
      for (int s = 0; s < 16; ++s)
        af[s] = load8_agent(rh_sh + lm*512 + lg*8 + s*32);
      f32x4 accc[2] = {};
      #pragma unroll
      for (int s = 0; s < 16; ++s)
        #pragma unroll
        for (int nt = 0; nt < 2; ++nt)
          accc[nt] = __builtin_amdgcn_mfma_f32_16x16x32_f16(af[s], uh[nt][s], accc[nt], 0, 0, 0);
      #pragma unroll
      for (int nt = 0; nt < 2; ++nt)
        #pragma unroll
        for (int i = 0; i < 4; ++i) {
          int row = lg*4 + i;
          float c  = 1.f - 2.f/(__expf(2.f*(accc[nt][i] + xh[nt][i])) + 1.f);
          float z  = zreg[nt][i];
          float hn = (1.f - z)*hreg[nt][i] + z*c;
          hreg[nt][i] = hn;
          if (t < S_ - 1) store2_agent(h_sh + row*512 + colg[nt], (f16)hn);
        }
      if (t < S_ - 1) {
        arrive3(f0t, 2*t + 1, nullptr, 0, j, l);
        PREFX(t + 1);
        STOREH0(t);           // off critical path; drained by next phase A arrive
        waitall16<false>(f0t, 2*t + 1, l);
      } else {
        #pragma unroll
        for (int nt = 0; nt < 2; ++nt)
          #pragma unroll
          for (int i = 0; i < 4; ++i)
            hfin0[(team*16 + lg*4 + i)*512 + colg[nt]] = hreg[nt][i];
        STOREH0(t);
        arrive3(f0t, 2*t + 1, f0pt, 2*t + 1, j, l);   // final: drain + publish both
      }
    }
    return;
  }

  // =========================== LAYER 1 ===========================
  f16* h_sh  = h1sh  + team*(16*512);
  f16* rh_sh = rh1sh + team*(16*512);

  f16x8 uh[2][16];        // consumer only
  f16x8 wx[3][16];        // producers only
  float bv[3];
  if (w == 0) {
    for (int i = l; i < 2*32*64; i += 64) {
      int g = i >> 11, rem = i & 2047;
      int c = rem >> 6, ch = rem & 63;
      f16x8 v = *(const f16x8*)(U1T + (size_t)(g*512 + j*32 + c)*512 + ch*8);
      *(f16x8*)(Us + g*16384 + c*512 + ((ch ^ (c & 7))*8)) = v;
    }
    #pragma unroll
    for (int nt = 0; nt < 2; ++nt)
      #pragma unroll
      for (int s = 0; s < 16; ++s)
        uh[nt][s] = *(const f16x8*)(U1T + (size_t)(1024 + j*32 + nt*16 + lm)*512 + s*32 + lg*8);
  } else {
    const int cb = (w - 1)*3;
    #pragma unroll
    for (int c = 0; c < 3; ++c) {
      int chunk = cb + c, g = chunk >> 1, ntl = chunk & 1;
      int row = g*512 + j*32 + ntl*16 + lm;
      bv[c] = bias1[row];
      #pragma unroll
      for (int s = 0; s < 16; ++s)
        wx[c][s] = *(const f16x8*)(W1xT + (size_t)row*512 + s*32 + lg*8);
    }
  }

  const int cb = (w - 1)*3;
  auto PROD = [&](int tt) {   // producers: xg1(tt) -> xgbuf[tt&1]
    waitall16<true>(f0pt, 2*(unsigned)tt + 1, l);    // shadow flags only, sleepy poll
    f16x8 af[16];
    #pragma unroll
    for (int s = 0; s < 16; ++s)
      af[s] = load8_agent(H0 + (size_t)(tt*64 + team*16 + lm)*512 + s*32 + lg*8);
    f32x4 acc[3] = {};
    #pragma unroll
    for (int s = 0; s < 16; ++s)
      #pragma unroll
      for (int c = 0; c < 3; ++c)
        acc[c] = __builtin_amdgcn_mfma_f32_16x16x32_f16(af[s], wx[c][s], acc[c], 0, 0, 0);
    #pragma unroll
    for (int c = 0; c < 3; ++c) {
      int chunk = cb + c, g = chunk >> 1, ntl = chunk & 1;
      #pragma unroll
      for (int i = 0; i < 4; ++i)
        xgbuf[tt & 1][lg*4 + i][g*32 + ntl*16 + lm] = (f16)(acc[c][i] + bv[c]);
    }
  };

  float hreg[2][4], zreg[2][4];

  __syncthreads();                    // init done
  if (w != 0) PROD(0);
  __syncthreads();                    // xg(0) ready

  // ---- t = 0
  if (w == 0) {
    #pragma unroll
    for (int nt = 0; nt < 2; ++nt)
      #pragma unroll
      for (int i = 0; i < 4; ++i) {
        int row = lg*4 + i;
        float xzv = (float)xgbuf[0][row][32 + nt*16 + lm];
        float xhv = (float)xgbuf[0][row][64 + nt*16 + lm];
        float z = 1.f/(1.f + __expf(-xzv));
        float c = 1.f - 2.f/(__expf(2.f*xhv) + 1.f);
        float hn = z*c;
        hreg[nt][i] = hn;
        f16 hv = (f16)hn;
        store2_agent(h_sh + row*512 + colg[nt], hv);
        H1[(size_t)(team*16 + row)*512 + colg[nt]] = hv;
      }
    arrive3(f1t, 1, nullptr, 0, j, l);
    waitall16<false>(f1t, 1, l);
  } else {
    PROD(1);
  }
  __syncthreads();                    // xg(1) ready, t=0 exchanged

  for (int t = 1; t < S_; ++t) {
    if (w == 0) {
      const int b = t & 1;
      // ---- phase A
      f16x8 af[16];
      #pragma unroll
      for (int s = 0; s < 16; ++s)
        af[s] = load8_agent(h_sh + lm*512 + lg*8 + s*32);
      f32x4 accr[2] = {}, accz[2] = {};
      #pragma unroll
      for (int s = 0; s < 16; ++s) {
        #pragma unroll
        for (int nt = 0; nt < 2; ++nt) {
          int colL = nt*16 + lm, ch = s*4 + lg;
          f16x8 br = *(const f16x8*)(Us +         colL*512 + ((ch ^ (colL & 7))*8));
          f16x8 bz = *(const f16x8*)(Us + 16384 + colL*512 + ((ch ^ (colL & 7))*8));
          accr[nt] = __builtin_amdgcn_mfma_f32_16x16x32_f16(af[s], br, accr[nt], 0, 0, 0);
          accz[nt] = __builtin_amdgcn_mfma_f32_16x16x32_f16(af[s], bz, accz[nt], 0, 0, 0);
        }
      }
      #pragma unroll
      for (int nt = 0; nt < 2; ++nt)
        #pragma unroll
        for (int i = 0; i < 4; ++i) {
          int row = lg*4 + i;
          float xrv = (float)xgbuf[b][row][     nt*16 + lm];
          float xzv = (float)xgbuf[b][row][32 + nt*16 + lm];
          float r = 1.f/(1.f + __expf(-(accr[nt][i] + xrv)));
          float z = 1.f/(1.f + __expf(-(accz[nt][i] + xzv)));
          zreg[nt][i] = z;
          store2_agent(rh_sh + row*512 + colg[nt], (f16)(r*hreg[nt][i]));
        }
      arrive3(f1t, 2*t, nullptr, 0, j, l);
      waitall16<false>(f1t, 2*t, l);

      // ---- phase B
      #pragma unroll
      for (int s = 0; s < 16; ++s)
        af[s] = load8_agent(rh_sh + lm*512 + lg*8 + s*32);
      f32x4 accc[2] = {};
      #pragma unroll
      for (int s = 0; s < 16; ++s)
        #pragma unroll
        for (int nt = 0; nt < 2; ++nt)
          accc[nt] = __builtin_amdgcn_mfma_f32_16x16x32_f16(af[s], uh[nt][s], accc[nt], 0, 0, 0);
      #pragma unroll
      for (int nt = 0; nt < 2; ++nt)
        #pragma unroll
        for (int i = 0; i < 4; ++i) {
          int row = lg*4 + i;
          float xhv = (float)xgbuf[b][row][64 + nt*16 + lm];
          float c  = 1.f - 2.f/(__expf(2.f*(accc[nt][i] + xhv)) + 1.f);
          float z  = zreg[nt][i];
          float hn = (1.f - z)*hreg[nt][i] + z*c;
          hreg[nt][i] = hn;
          f16 hv = (f16)hn;
          if (t < S_ - 1) store2_agent(h_sh + row*512 + colg[nt], hv);
          H1[(size_t)(t*64 + team*16 + row)*512 + colg[nt]] = hv;
        }
      if (t < S_ - 1) {
        arrive3(f1t, 2*t + 1, nullptr, 0, j, l);
        waitall16<false>(f1t, 2*t + 1, l);
      } else {
        #pragma unroll
        for (int nt = 0; nt < 2; ++nt)
          #pragma unroll
          for (int i = 0; i < 4; ++i)
            hfin1[(team*16 + lg*4 + i)*512 + colg[nt]] = hreg[nt][i];
      }
    } else if (t + 1 < S_) {
      PROD(t + 1);
    }
    __syncthreads();
  }
}

// ======================= launch =======================
extern "C" void kernel_launch(void* const* d_in, const int* in_sizes, int n_in,
                              void* d_out, int out_size, void* d_ws, size_t ws_size,
                              hipStream_t stream) {
  const int*   tok  = (const int*)d_in[0];
  const float* emb  = (const float*)d_in[2];
  const float* Wr0  = (const float*)d_in[3];
  const float* br0  = (const float*)d_in[4];
  const float* Wz0  = (const float*)d_in[5];
  const float* bz0  = (const float*)d_in[6];
  const float* Wh0  = (const float*)d_in[7];
  const float* bh0  = (const float*)d_in[8];
  const float* Wr1  = (const float*)d_in[9];
  const float* br1  = (const float*)d_in[10];
  const float* Wz1  = (const float*)d_in[11];
  const float* bz1  = (const float*)d_in[12];
  const float* Wh1  = (const float*)d_in[13];
  const float* bh1  = (const float*)d_in[14];
  const float* Wout = (const float*)d_in[15];
  const float* bout = (const float*)d_in[16];

  char* ws = (char*)d_ws;
  size_t off = 0;
  auto alloc = [&](size_t bytes) { void* p = ws + off; off = (off + bytes + 255) & ~(size_t)255; return p; };
  f16* X     = (f16*)alloc((size_t)M_*E_*2);
  f16* W0xT  = (f16*)alloc((size_t)1536*256*2);
  f16* U0T   = (f16*)alloc((size_t)1536*512*2);
  f16* W1xT  = (f16*)alloc((size_t)1536*512*2);
  f16* U1T   = (f16*)alloc((size_t)1536*512*2);
  f16* WoutT = (f16*)alloc((size_t)VPAD*512*2);
  f16* XG    = (f16*)alloc((size_t)M_*1536*2);
  f16* H0    = (f16*)alloc((size_t)M_*512*2);
  f16* H1    = (f16*)alloc((size_t)M_*512*2);
  f16* h0sh  = (f16*)alloc(4*16*512*2);
  f16* rh0sh = (f16*)alloc(4*16*512*2);
  f16* h1sh  = (f16*)alloc(4*16*512*2);
  f16* rh1sh = (f16*)alloc(4*16*512*2);
  float* bias0 = (float*)alloc(1536*4);
  float* bias1 = (float*)alloc(1536*4);
  unsigned int* flags0  = (unsigned int*)alloc(4*16*FSTRIDE*4);
  unsigned int* flags0p = (unsigned int*)alloc(4*16*FSTRIDE*4);
  unsigned int* flags1  = (unsigned int*)alloc(4*16*FSTRIDE*4);

  float* logits = (float*)d_out;
  float* hfin0  = logits + (size_t)M_*V_;     // [2][64][512] tail
  float* hfin1  = hfin0 + 64*512;

  hipMemsetAsync(flags0,  0, 4*16*FSTRIDE*4, stream);
  hipMemsetAsync(flags0p, 0, 4*16*FSTRIDE*4, stream);
  hipMemsetAsync(flags1,  0, 4*16*FSTRIDE*4, stream);

  k_trans3<<<(1536*256 + 255)/256, 256, 0, stream>>>(Wr0, Wz0, Wh0, W0xT, 256, 0);
  k_trans3<<<(1536*512 + 255)/256, 256, 0, stream>>>(Wr0, Wz0, Wh0, U0T, 512, 256);
  k_trans3<<<(1536*512 + 255)/256, 256, 0, stream>>>(Wr1, Wz1, Wh1, W1xT, 512, 0);
  k_trans3<<<(1536*512 + 255)/256, 256, 0, stream>>>(Wr1, Wz1, Wh1, U1T, 512, 512);
  { dim3 g(VPAD/32, 512/32); k_transW<<<g, 256, 0, stream>>>(Wout, WoutT); }
  k_gatherX<<<(M_*E_)/256, 256, 0, stream>>>(tok, emb, X);
  k_bias<<<6, 256, 0, stream>>>(br0, bz0, bh0, br1, bz1, bh1, bias0, bias1);

  dim3 gx(M_/128, 1536/128);
  k_gemm<false><<<gx, 256, 0, stream>>>(X, W0xT, bias0, XG, 1536, 256, 1536);

  k_recur_fused<<<128, 192, 0, stream>>>(XG, U0T, U1T, W1xT, bias1,
                                         H0, H1, hfin0, hfin1,
                                         h0sh, rh0sh, h1sh, rh1sh,
                                         flags0, flags0p, flags1);

  dim3 gl(M_/128, VPAD/128);
  k_gemm<true><<<gl, 256, 0, stream>>>(H1, WoutT, bout, logits, V_, 512, V_);
}